// Round 5
// baseline (3598.916 us; speedup 1.0000x reference)
//
#include <hip/hip_runtime.h>

#define TT 256         // time steps
#define VV 5000        // vocab
#define NC4 1250       // VV/4 float4 chunks per row
#define BEAMW 16
#define WASR 0.7f
#define WLM 0.3f
#define SOS_TOK 1
#define CAP 512
#define LK 256         // sorted list length (theta chosen to fit)
#define CH0 48         // A-side chunk gathered unconditionally

// ws float offsets
#define OFF_LSTAT4 0                     // float4[VV]: {m, logS, theta_raw, lbnd}
#define OFF_AM     (4*VV)                // [TT]
#define OFF_ALS    (4*VV + TT)           // [TT]
#define OFF_ABND   (4*VV + 2*TT)         // [TT]
#define OFF_LISTS  (4*VV + 3*TT)         // float2 L[VV][LK] then A[TT][LK]

static inline size_t ws_need_floats() {
  return (size_t)OFF_LISTS + 2ull * (VV + TT) * LK;   // ~10.85 MB total
}

// ---------------- prep: row stats + sorted shortlists (theta fits LK) ----------
__global__ __launch_bounds__(256) void prep_kernel(
    const float* __restrict__ asr, const float* __restrict__ lm,
    float* __restrict__ ws, int build)
{
  __shared__ float sm[8];
  __shared__ int   hist[256];
  __shared__ float s_theta;
  __shared__ int   s_cnt;
  __shared__ int   s_ok;
  __shared__ float s_sv[LK];
  __shared__ int   s_tk[LK];
  __shared__ float s_sv2[LK];
  __shared__ int   s_tk2[LK];

  const int row = blockIdx.x;
  const bool is_lm = (row < VV);
  const int t = row - VV;
  const float* src = is_lm ? (lm + (size_t)row * VV) : (asr + (size_t)t * VV);
  const float4* s4 = (const float4*)src;
  const int tid = (int)threadIdx.x;

  float4 x[5];
  float m = -INFINITY;
#pragma unroll
  for (int k = 0; k < 5; ++k) {
    int c = tid + 256 * k;
    if (c < NC4) {
      x[k] = s4[c];
      m = fmaxf(m, fmaxf(fmaxf(x[k].x, x[k].y), fmaxf(x[k].z, x[k].w)));
    }
  }
#pragma unroll
  for (int j = 1; j < 64; j <<= 1) m = fmaxf(m, __shfl_xor(m, j, 64));
  if ((tid & 63) == 0) sm[tid >> 6] = m;
  __syncthreads();
  m = fmaxf(fmaxf(sm[0], sm[1]), fmaxf(sm[2], sm[3]));
  __syncthreads();

  float ssum = 0.f;
#pragma unroll
  for (int k = 0; k < 5; ++k) {
    int c = tid + 256 * k;
    if (c < NC4) {
      ssum += expf(x[k].x - m);
      ssum += expf(x[k].y - m);
      ssum += expf(x[k].z - m);
      ssum += expf(x[k].w - m);
    }
  }
#pragma unroll
  for (int j = 1; j < 64; j <<= 1) ssum += __shfl_xor(ssum, j, 64);
  if ((tid & 63) == 0) sm[4 + (tid >> 6)] = ssum;
  __syncthreads();
  ssum = (sm[4] + sm[5]) + (sm[6] + sm[7]);
  const float logS = logf(ssum);

  if (!build) {
    if (tid == 0) {
      if (is_lm) ((float4*)(ws + OFF_LSTAT4))[row] = make_float4(m, logS, 0.f, 0.f);
      else { ws[OFF_AM + t] = m; ws[OFF_ALS + t] = logS; }
    }
    return;
  }
  if (!is_lm && tid == 0) { ws[OFF_AM + t] = m; ws[OFF_ALS + t] = logS; }

  // histogram of y = m - x, 256 bins of width 1/16
  hist[tid] = 0;
  __syncthreads();
#pragma unroll
  for (int k = 0; k < 5; ++k) {
    int c = tid + 256 * k;
    if (c < NC4) {
      float vv[4] = {x[k].x, x[k].y, x[k].z, x[k].w};
#pragma unroll
      for (int j = 0; j < 4; ++j) {
        float y = m - vv[j];
        int b = (int)(y * 16.0f);
        b = b < 0 ? 0 : (b > 255 ? 255 : b);
        atomicAdd(&hist[b], 1);
      }
    }
  }
  __syncthreads();
  if (tid == 0) {
    int c = 0, bs = -1;
    for (int b = 0; b < 256; ++b) {
      c += hist[b];
      if (c <= LK) bs = b; else break;
    }
    s_theta = (bs >= 0) ? m - (float)(bs + 1) * 0.0625f : INFINITY;
    s_ok = (bs >= 0) ? 1 : 0;
    s_cnt = 0;
  }
  __syncthreads();
  const float theta = s_theta;
  const float wgt = is_lm ? WLM : WASR;

  if (s_ok) {
#pragma unroll
    for (int k = 0; k < 5; ++k) {
      int c = tid + 256 * k;
      if (c < NC4) {
        float vv[4] = {x[k].x, x[k].y, x[k].z, x[k].w};
#pragma unroll
        for (int j = 0; j < 4; ++j) {
          float xv = vv[j];
          if (xv >= theta) {
            int p = atomicAdd(&s_cnt, 1);
            if (p < LK) {
              float sv = __fmul_rn(wgt, __fsub_rn(__fsub_rn(xv, m), logS));
              s_sv[p] = sv; s_tk[p] = c * 4 + j;
            }
          }
        }
      }
    }
  }
  __syncthreads();
  const int cnt = s_cnt;
  const bool ovf = (!s_ok) || (cnt > LK);
  const int nv = ovf ? 0 : cnt;

  // rank-sort (sv desc, tok asc) — exact lex order
  if (tid < nv) {
    float v = s_sv[tid]; int tk = s_tk[tid];
    int r = 0;
    for (int j = 0; j < nv; ++j) {
      float vj = s_sv[j];
      r += ((vj > v) || (vj == v && s_tk[j] < tk)) ? 1 : 0;
    }
    s_sv2[r] = v; s_tk2[r] = tk;
  }
  __syncthreads();

  float2* Llists = (float2*)(ws + OFF_LISTS);
  float2* dst = is_lm ? (Llists + (size_t)row * LK)
                      : (Llists + (size_t)VV * LK + (size_t)t * LK);
  for (int p = tid; p < LK; p += 256)
    dst[p] = (p < nv) ? make_float2(s_sv2[p], __int_as_float(s_tk2[p]))
                      : make_float2(-1e30f, __int_as_float(0x7FFFFFFF));

  if (tid == 0) {
    float thO = ovf ? INFINITY : theta;
    float bnd = ovf ? INFINITY : __fmul_rn(wgt, __fsub_rn(__fsub_rn(theta, m), logS));
    if (is_lm) ((float4*)(ws + OFF_LSTAT4))[row] = make_float4(m, logS, thO, bnd);
    else       ws[OFF_ABND + t] = bnd;
  }
}

// ---------------- helpers ----------------
__device__ __forceinline__ float bitonic64_desc_val(float v, int lane) {
#pragma unroll
  for (int kk = 2; kk <= 64; kk <<= 1)
#pragma unroll
    for (int j = kk >> 1; j > 0; j >>= 1) {
      float o = __shfl_xor(v, j, 64);
      bool keepMax = (((lane & kk) == 0) == ((lane & j) == 0));
      v = keepMax ? fmaxf(v, o) : fminf(v, o);
    }
  return v;
}

__device__ __forceinline__ void bitonic64_desc_pair(float& bv, int& bi, int lane) {
#pragma unroll
  for (int kk = 2; kk <= 64; kk <<= 1)
#pragma unroll
    for (int j = kk >> 1; j > 0; j >>= 1) {
      float ov = __shfl_xor(bv, j, 64);
      int   oi = __shfl_xor(bi, j, 64);
      bool keepTop = (((lane & kk) == 0) == ((lane & j) == 0));
      bool mineBetter = (bv > ov) || (bv == ov && bi < oi);
      if (keepTop != mineBetter) { bv = ov; bi = oi; }
    }
}

__device__ __forceinline__ float cand_val(float s, float a, float am, float als,
                                          float x, float mB, float lsB) {
  float av = __fmul_rn(WASR, __fsub_rn(__fsub_rn(a, am), als));
  float lv = __fmul_rn(WLM,  __fsub_rn(__fsub_rn(x, mB), lsB));
  return __fadd_rn(__fadd_rn(s, av), lv);
}

// ---------------- fast beam kernel: LDS Aw row + chunked A-side gathers ----------
__global__ __launch_bounds__(1024, 4) void beam_fast(
    const float* __restrict__ asr, const float* __restrict__ lm,
    const float* __restrict__ ws, float* __restrict__ out)
{
  __shared__ float4 s_aw4[2][1252];        // scaled A row (float view), dbuf
  __shared__ float2 s_al[2][LK];           // sorted A-list, dbuf
  __shared__ float  s_scores[BEAMW];
  __shared__ int    s_last[BEAMW];
  __shared__ float4 s_lstat[BEAMW];        // {mB, lsB, thL, lbnd}
  __shared__ float  s_am[TT], s_als[TT], s_abnd[TT];
  __shared__ float  s_tau[BEAMW];
  __shared__ float  s_m2v[64];
  __shared__ int    s_m2i[64];
  __shared__ float  s_bufval[CAP];
  __shared__ int    s_bufidx[CAP];
  __shared__ int    s_cnt;
  __shared__ int    s_flags;
  __shared__ float  s_selv[BEAMW];
  __shared__ int    s_seli[BEAMW];
  __shared__ float  s_tau16;
  __shared__ unsigned short s_toks[TT * BEAMW];
  __shared__ unsigned char  s_bps[TT * BEAMW];

  const int tid = (int)threadIdx.x;
  const int lane = tid & 63;
  const int w = tid >> 6;
  const float2* __restrict__ Llists = (const float2*)(ws + OFF_LISTS);
  const float2* __restrict__ Alists = Llists + (size_t)VV * LK;
  const float4* __restrict__ lstat4 = (const float4*)(ws + OFF_LSTAT4);

  if (tid < TT) {
    s_am[tid]   = ws[OFF_AM + tid];
    s_als[tid]  = ws[OFF_ALS + tid];
    s_abnd[tid] = ws[OFF_ABND + tid];
  }
  if (tid == 0) { s_cnt = 0; s_flags = 0; }
  __syncthreads();

  // initial staging: Aw row 0 + A-list 0
  {
    const float4* a4 = (const float4*)asr;     // row 0 of asr
    float am0 = s_am[0], als0 = s_als[0];
    float4 g0 = a4[tid];
    bool h1 = tid < (NC4 - 1024);
    float4 g1 = a4[h1 ? 1024 + tid : 0];
    float4 r0, r1;
    r0.x = __fmul_rn(WASR, __fsub_rn(__fsub_rn(g0.x, am0), als0));
    r0.y = __fmul_rn(WASR, __fsub_rn(__fsub_rn(g0.y, am0), als0));
    r0.z = __fmul_rn(WASR, __fsub_rn(__fsub_rn(g0.z, am0), als0));
    r0.w = __fmul_rn(WASR, __fsub_rn(__fsub_rn(g0.w, am0), als0));
    s_aw4[0][tid] = r0;
    if (h1) {
      r1.x = __fmul_rn(WASR, __fsub_rn(__fsub_rn(g1.x, am0), als0));
      r1.y = __fmul_rn(WASR, __fsub_rn(__fsub_rn(g1.y, am0), als0));
      r1.z = __fmul_rn(WASR, __fsub_rn(__fsub_rn(g1.z, am0), als0));
      r1.w = __fmul_rn(WASR, __fsub_rn(__fsub_rn(g1.w, am0), als0));
      s_aw4[0][1024 + tid] = r1;
    }
    if (tid < LK) s_al[0][tid] = Alists[tid];
  }
  if (tid < BEAMW) {
    s_scores[tid] = (tid == 0) ? 0.0f : -1e30f;
    s_last[tid]   = SOS_TOK;
    s_lstat[tid]  = lstat4[SOS_TOK];
  }
  __syncthreads();
  int cur = 0;

  // wave0: rank-select top-16 (val desc, flat asc) from array of nn <= 64
  auto rank_sel = [&](const float* sva, const int* sia, int nn) {
    float bv = (lane < nn) ? sva[lane] : -INFINITY;
    int   bi = (lane < nn) ? sia[lane] : 0x7FFFFFFF;
    int r = 0;
#pragma unroll 4
    for (int j = 0; j < nn; ++j) {
      float vj = sva[j]; int ij = sia[j];
      r += ((vj > bv) || (vj == bv && ij < bi)) ? 1 : 0;
    }
    if (lane < nn && r < BEAMW) {
      s_selv[r] = bv; s_seli[r] = bi;
      if (r == BEAMW - 1) s_tau16 = bv;
    }
  };
  // waves 0-3: per-64-segment top-16 into s_m2 (64 < nn <= 256)
  auto seg_phase = [&](int nn) {
    if (w < 4) {
      int base = w << 6;
      int lim = nn - base; lim = lim < 0 ? 0 : (lim > 64 ? 64 : lim);
      float bv = (lane < lim) ? s_bufval[base + lane] : -INFINITY;
      int   bi = (lane < lim) ? s_bufidx[base + lane] : 0x7FFFFFFF;
      int r = 0;
#pragma unroll 4
      for (int j = 0; j < lim; ++j) {
        float vj = s_bufval[base + j]; int ij = s_bufidx[base + j];
        r += ((vj > bv) || (vj == bv && ij < bi)) ? 1 : 0;
      }
      if (lane < lim && r < BEAMW) { s_m2v[(w << 4) | r] = bv; s_m2i[(w << 4) | r] = bi; }
      if (lane >= lim && lane < BEAMW) { s_m2v[(w << 4) | lane] = -INFINITY; s_m2i[(w << 4) | lane] = 0x7FFFFFFF; }
    }
  };
  // wave0: exact iterative extraction for nn in (256, CAP]
  auto iter_sel = [&](int nn) {
    float pv = -INFINITY; int pi = 0x7FFFFFFF;
    for (int it = 0; it < BEAMW; ++it) {
      float cvv = -INFINITY; int cii = 0x7FFFFFFF;
      for (int k2 = 0; k2 < CAP / 64; ++k2) {
        int p = lane + (k2 << 6);
        if (p < nn) {
          float vv2 = s_bufval[p]; int ii2 = s_bufidx[p];
          bool lessPrev = (it == 0) || (vv2 < pv) || (vv2 == pv && ii2 > pi);
          bool better = (vv2 > cvv) || (vv2 == cvv && ii2 < cii);
          if (lessPrev && better) { cvv = vv2; cii = ii2; }
        }
      }
      for (int j = 1; j < 64; j <<= 1) {
        float ov = __shfl_xor(cvv, j, 64); int oi = __shfl_xor(cii, j, 64);
        bool ob = (ov > cvv) || (ov == cvv && oi < cii);
        if (ob) { cvv = ov; cii = oi; }
      }
      if (lane == 0) { s_selv[it] = cvv; s_seli[it] = cii; if (it == BEAMW - 1) s_tau16 = cvv; }
      pv = cvv; pi = cii;
    }
  };
  // wave0: commit selection to state + history
  auto commit_w0 = [&](int t_) {
    if (lane < BEAMW) {
      float val = s_selv[lane]; int flat = s_seli[lane];
      int bb = flat / VV; int tk = flat - bb * VV;
      float4 st2 = lstat4[tk];
      s_scores[lane] = val; s_last[lane] = tk; s_lstat[lane] = st2;
      s_toks[t_ * BEAMW + lane] = (unsigned short)tk;
      s_bps[t_ * BEAMW + lane]  = (unsigned char)bb;
    }
  };

  for (int t = 0; t < TT; ++t) {
    const int nxt = (t + 1 < TT) ? (t + 1) : t;
    // loop-top state (held in registers across commit for the redo path)
    const float s = s_scores[w];
    const int last = s_last[w];
    const float4 st = s_lstat[w];
    const float mB = st.x, lsB = st.y, thL = st.z, lbnd = st.w;
    const float am = s_am[t], als = s_als[t];
    const float* awc = (const float*)s_aw4[cur];
    const float2* __restrict__ Ll = Llists + (size_t)last * LK;

    // ---- issue loads ----
    float2 le0 = Ll[lane];
    float2 le1 = Ll[64 + lane];
    float2 le2 = Ll[128 + lane];
    float2 le3 = Ll[192 + lane];
    float2 ae = s_al[cur][lane];
    int atok = __float_as_int(ae.y);
    bool av_ok = (lane < CH0) && (ae.x > -9e29f);
    float gm = lm[(size_t)last * VV + (av_ok ? atok : 0)];
    // staging loads for step t+1 (off critical path; known statically)
    const float4* an4 = (const float4*)(asr + (size_t)nxt * VV);
    float4 g0 = an4[tid];
    bool h1 = tid < (NC4 - 1024);
    float4 g1 = an4[h1 ? 1024 + tid : 0];
    float2 ga = (tid < LK) ? Alists[(size_t)nxt * LK + tid] : make_float2(0.f, 0.f);

    // ---- L-side candidates (pure LDS lookups) ----
    float cv0, cv1, cv2, cv3;
    {
      bool v0 = le0.x > -9e29f; int t0 = __float_as_int(le0.y);
      bool v1 = le1.x > -9e29f; int t1 = __float_as_int(le1.y);
      bool v2 = le2.x > -9e29f; int t2 = __float_as_int(le2.y);
      bool v3 = le3.x > -9e29f; int t3 = __float_as_int(le3.y);
      float a0 = awc[v0 ? t0 : 0], a1 = awc[v1 ? t1 : 0];
      float a2 = awc[v2 ? t2 : 0], a3 = awc[v3 ? t3 : 0];
      cv0 = v0 ? __fadd_rn(__fadd_rn(s, a0), le0.x) : -INFINITY;
      cv1 = v1 ? __fadd_rn(__fadd_rn(s, a1), le1.x) : -INFINITY;
      cv2 = v2 ? __fadd_rn(__fadd_rn(s, a2), le2.x) : -INFINITY;
      cv3 = v3 ? __fadd_rn(__fadd_rn(s, a3), le3.x) : -INFINITY;
    }
    // ---- A-side chunk (gathered lm values) ----
    float svr = __fmul_rn(WLM, __fsub_rn(__fsub_rn(gm, mB), lsB));
    bool inL = (gm >= thL);                         // exact L-list membership
    float cva = (av_ok && !inL) ? __fadd_rn(__fadd_rn(s, ae.x), svr) : -INFINITY;

    // ---- per-wave 16th-largest lane-max ----
    float lmax = fmaxf(fmaxf(fmaxf(cv0, cv1), fmaxf(cv2, cv3)), cva);
    float vs = bitonic64_desc_val(lmax, lane);
    if (lane == 15) s_tau[w] = vs;
    __syncthreads();                                 // A

    float tg = s_tau[0];
#pragma unroll
    for (int b = 1; b < BEAMW; ++b) tg = fmaxf(tg, s_tau[b]);

    // ---- refinement count: j* = #{j: (s+ae[j].x)+lbnd >= tg} (monotone) ----
    int cnt = 0;
#pragma unroll
    for (int r = 0; r < 4; ++r) {
      float bx = s_al[cur][(r << 6) + lane].x;
      bool p = (__fadd_rn(__fadd_rn(s, bx), lbnd) >= tg);
      cnt += (int)__popcll(__ballot(p));
    }
    int extra = cnt - CH0;
    if (extra > 64) { if (lane == 0) atomicOr(&s_flags, 1); extra = 0; }  // redo

    // ---- append survivors ----
    if (cv0 >= tg) { int p = atomicAdd(&s_cnt, 1); if (p < CAP) { s_bufval[p] = cv0; s_bufidx[p] = w * VV + __float_as_int(le0.y); } }
    if (cv1 >= tg) { int p = atomicAdd(&s_cnt, 1); if (p < CAP) { s_bufval[p] = cv1; s_bufidx[p] = w * VV + __float_as_int(le1.y); } }
    if (cv2 >= tg) { int p = atomicAdd(&s_cnt, 1); if (p < CAP) { s_bufval[p] = cv2; s_bufidx[p] = w * VV + __float_as_int(le2.y); } }
    if (cv3 >= tg) { int p = atomicAdd(&s_cnt, 1); if (p < CAP) { s_bufval[p] = cv3; s_bufidx[p] = w * VV + __float_as_int(le3.y); } }
    if (cva >= tg) { int p = atomicAdd(&s_cnt, 1); if (p < CAP) { s_bufval[p] = cva; s_bufidx[p] = w * VV + atok; } }
    if (extra > 0) {                                   // rare stragglers [CH0, cnt)
      bool ex_ok = lane < extra;
      float2 ae2 = s_al[cur][ex_ok ? CH0 + lane : 0];
      int atok2 = __float_as_int(ae2.y);
      float gm2 = lm[(size_t)last * VV + (ex_ok ? atok2 : 0)];
      float svr2 = __fmul_rn(WLM, __fsub_rn(__fsub_rn(gm2, mB), lsB));
      bool inL2 = (gm2 >= thL);
      float cva2 = (ex_ok && !inL2) ? __fadd_rn(__fadd_rn(s, ae2.x), svr2) : -INFINITY;
      if (cva2 >= tg) { int p = atomicAdd(&s_cnt, 1); if (p < CAP) { s_bufval[p] = cva2; s_bufidx[p] = w * VV + atok2; } }
    }
    __syncthreads();                                 // B

    const int n = s_cnt;
    const int nc = n > CAP ? CAP : n;
    if (nc > 64 && nc <= 256) seg_phase(nc);
    __syncthreads();                                 // C1

    if (w == 0) {
      if (nc <= 64)       rank_sel(s_bufval, s_bufidx, nc);
      else if (nc <= 256) rank_sel(s_m2v, s_m2i, 64);
      else                iter_sel(nc);
      float t16 = s_tau16;
      bool rf = false;
      if (lane < BEAMW) {
        float sb = s_scores[lane];         // OLD scores (pre-commit)
        float lb2 = s_lstat[lane].w;
        rf = (__fadd_rn(__fadd_rn(sb, s_abnd[t]), lb2) >= t16);  // class-(ii) bound
      }
      unsigned long long mk = __ballot(rf);
      if (lane == 0 && (mk != 0ull || n > CAP)) atomicOr(&s_flags, 2);
      commit_w0(t);
    }
    __syncthreads();                                 // C2

    if (s_flags) {
      // ---- exact full scan of all 16 rows (uses loop-top registers) ----
      if (tid == 0) s_cnt = 0;
      const float4* A4p = (const float4*)(asr + (size_t)t * VV);
      const float4* L4p = (const float4*)(lm + (size_t)last * VV);
      float chm[20]; float rowm = -INFINITY;
#pragma unroll
      for (int k = 0; k < 20; ++k) {
        int c = lane + (k << 6);
        bool ok = (c < NC4);
        int cc = ok ? c : 0;
        float4 a4 = A4p[cc]; float4 l4 = L4p[cc];
        float vx = cand_val(s, a4.x, am, als, l4.x, mB, lsB);
        float vy = cand_val(s, a4.y, am, als, l4.y, mB, lsB);
        float vz = cand_val(s, a4.z, am, als, l4.z, mB, lsB);
        float vw = cand_val(s, a4.w, am, als, l4.w, mB, lsB);
        float cm = fmaxf(fmaxf(vx, vy), fmaxf(vz, vw));
        if (!ok) cm = -INFINITY;
        chm[k] = cm; rowm = fmaxf(rowm, cm);
      }
      float vsr = bitonic64_desc_val(rowm, lane);
      if (lane == 15) s_tau[w] = vsr;
      __syncthreads();
      float tg2 = s_tau[0];
#pragma unroll
      for (int b = 1; b < BEAMW; ++b) tg2 = fmaxf(tg2, s_tau[b]);
#pragma unroll
      for (int k = 0; k < 20; ++k) {
        if (chm[k] >= tg2) {
          int c = lane + (k << 6);
          float4 a4 = A4p[c]; float4 l4 = L4p[c];
          float ar4[4] = {a4.x, a4.y, a4.z, a4.w};
          float lr4[4] = {l4.x, l4.y, l4.z, l4.w};
#pragma unroll
          for (int i = 0; i < 4; ++i) {
            float v = cand_val(s, ar4[i], am, als, lr4[i], mB, lsB);
            if (v >= tg2) {
              int p = atomicAdd(&s_cnt, 1);
              if (p < CAP) { s_bufval[p] = v; s_bufidx[p] = w * VV + c * 4 + i; }
            }
          }
        }
      }
      __syncthreads();
      int n2 = s_cnt; int n2c = n2 > CAP ? CAP : n2;
      if (n2c > 64 && n2c <= 256) seg_phase(n2c);
      __syncthreads();
      if (w == 0) {
        if (n2c <= 64)       rank_sel(s_bufval, s_bufidx, n2c);
        else if (n2c <= 256) rank_sel(s_m2v, s_m2i, 64);
        else                 iter_sel(n2c);
        commit_w0(t);
      }
    }

    // ---- staging writes for step t+1 ----
    {
      float am1 = s_am[nxt], als1 = s_als[nxt];
      float4 r0, r1;
      r0.x = __fmul_rn(WASR, __fsub_rn(__fsub_rn(g0.x, am1), als1));
      r0.y = __fmul_rn(WASR, __fsub_rn(__fsub_rn(g0.y, am1), als1));
      r0.z = __fmul_rn(WASR, __fsub_rn(__fsub_rn(g0.z, am1), als1));
      r0.w = __fmul_rn(WASR, __fsub_rn(__fsub_rn(g0.w, am1), als1));
      s_aw4[cur ^ 1][tid] = r0;
      if (h1) {
        r1.x = __fmul_rn(WASR, __fsub_rn(__fsub_rn(g1.x, am1), als1));
        r1.y = __fmul_rn(WASR, __fsub_rn(__fsub_rn(g1.y, am1), als1));
        r1.z = __fmul_rn(WASR, __fsub_rn(__fsub_rn(g1.z, am1), als1));
        r1.w = __fmul_rn(WASR, __fsub_rn(__fsub_rn(g1.w, am1), als1));
        s_aw4[cur ^ 1][1024 + tid] = r1;
      }
      if (tid < LK) s_al[cur ^ 1][tid] = ga;
    }
    if (tid == 0) { s_cnt = 0; s_flags = 0; }
    __syncthreads();                                 // D
    cur ^= 1;
  }

  if (tid < BEAMW) {
    out[tid] = s_scores[tid];
    int ptr = tid;
    for (int t = TT - 1; t >= 0; --t) {
      int tok = (int)s_toks[t * BEAMW + ptr];
      out[BEAMW + tid * TT + t] = (float)tok;
      ptr = (int)s_bps[t * BEAMW + ptr];
    }
  }
}

// ---------------- fallback: full-scan kernel (ws too small for lists) ----
__global__ __launch_bounds__(1024, 4) void beam_slow(
    const float* __restrict__ asr, const float* __restrict__ lm,
    const float* __restrict__ ws, float* __restrict__ out)
{
  __shared__ float s_scores[BEAMW];
  __shared__ int   s_last[BEAMW];
  __shared__ float s_lmm[BEAMW], s_lmls[BEAMW];
  __shared__ float s_tau[BEAMW];
  __shared__ float s_bufval[CAP];
  __shared__ int   s_bufidx[CAP];
  __shared__ int   s_cnt;
  __shared__ unsigned short s_toks[TT * BEAMW];
  __shared__ unsigned char  s_bps[TT * BEAMW];

  const int tid = (int)threadIdx.x;
  const int lane = tid & 63;
  const int w = tid >> 6;
  const float4* __restrict__ lstat4 = (const float4*)(ws + OFF_LSTAT4);

  if (tid < BEAMW) {
    s_scores[tid] = (tid == 0) ? 0.0f : -1e30f;
    s_last[tid] = SOS_TOK;
    float4 st = lstat4[SOS_TOK];
    s_lmm[tid] = st.x; s_lmls[tid] = st.y;
  }
  if (tid == 0) s_cnt = 0;
  __syncthreads();

  for (int t = 0; t < TT; ++t) {
    const float s = s_scores[w];
    const float mB = s_lmm[w], lsB = s_lmls[w];
    const int lastb = s_last[w];
    const float am = ws[OFF_AM + t], als = ws[OFF_ALS + t];
    const float4* __restrict__ L4p = (const float4*)(lm + (size_t)lastb * VV);
    const float4* __restrict__ A4p = (const float4*)(asr + (size_t)t * VV);

    float chm[20]; float rowm = -INFINITY;
#pragma unroll
    for (int k = 0; k < 20; ++k) {
      int c = lane + 64 * k;
      bool ok = (c < NC4);
      int cc = ok ? c : 0;
      float4 A4 = A4p[cc]; float4 L4 = L4p[cc];
      float vx = cand_val(s, A4.x, am, als, L4.x, mB, lsB);
      float vy = cand_val(s, A4.y, am, als, L4.y, mB, lsB);
      float vz = cand_val(s, A4.z, am, als, L4.z, mB, lsB);
      float vw = cand_val(s, A4.w, am, als, L4.w, mB, lsB);
      float cm = fmaxf(fmaxf(vx, vy), fmaxf(vz, vw));
      if (!ok) cm = -INFINITY;
      chm[k] = cm; rowm = fmaxf(rowm, cm);
    }
    {
      float v = bitonic64_desc_val(rowm, lane);
      if (lane == 15) s_tau[w] = v;
    }
    if (tid == 0) s_cnt = 0;
    __syncthreads();

    float tg = s_tau[lane & 15];
#pragma unroll
    for (int j = 1; j <= 8; j <<= 1) tg = fmaxf(tg, __shfl_xor(tg, j, 64));

#pragma unroll
    for (int k = 0; k < 20; ++k) {
      if (chm[k] >= tg) {
        int c = lane + 64 * k;
        float4 A4 = A4p[c]; float4 L4 = L4p[c];
        float ar4[4] = {A4.x, A4.y, A4.z, A4.w};
        float lr4[4] = {L4.x, L4.y, L4.z, L4.w};
#pragma unroll
        for (int i = 0; i < 4; ++i) {
          float v = cand_val(s, ar4[i], am, als, lr4[i], mB, lsB);
          if (v >= tg) {
            int p = atomicAdd(&s_cnt, 1);
            if (p < CAP) { s_bufval[p] = v; s_bufidx[p] = w * VV + c * 4 + i; }
          }
        }
      }
    }
    __syncthreads();

    if (w == 0) {
      int n = s_cnt; if (n > CAP) n = CAP;
      if (n <= 64) {
        float bv = (lane < n) ? s_bufval[lane] : -INFINITY;
        int   bi = (lane < n) ? s_bufidx[lane] : 0x7FFFFFFF;
        bitonic64_desc_pair(bv, bi, lane);
        if (lane < BEAMW) {
          int flat = bi;
          int bb = flat / VV; int tok = flat - bb * VV;
          float4 st = lstat4[tok];
          s_scores[lane] = bv; s_last[lane] = tok;
          s_lmm[lane] = st.x; s_lmls[lane] = st.y;
          s_toks[t * BEAMW + lane] = (unsigned short)tok;
          s_bps[t * BEAMW + lane] = (unsigned char)bb;
        }
      } else {
        float pv = -INFINITY; int pi = 0x7FFFFFFF;
        for (int it = 0; it < BEAMW; ++it) {
          float cvv = -INFINITY; int cii = 0x7FFFFFFF;
          for (int k2 = 0; k2 < CAP / 64; ++k2) {
            int p = lane + 64 * k2;
            if (p < n) {
              float vv2 = s_bufval[p]; int ii2 = s_bufidx[p];
              bool lessPrev = (it == 0) || (vv2 < pv) || (vv2 == pv && ii2 > pi);
              bool better = (vv2 > cvv) || (vv2 == cvv && ii2 < cii);
              if (lessPrev && better) { cvv = vv2; cii = ii2; }
            }
          }
          for (int j = 1; j < 64; j <<= 1) {
            float ov = __shfl_xor(cvv, j, 64); int oi = __shfl_xor(cii, j, 64);
            bool ob = (ov > cvv) || (ov == cvv && oi < cii);
            if (ob) { cvv = ov; cii = oi; }
          }
          if (lane == 0) {
            int bb = cii / VV; int tok = cii - bb * VV;
            float4 st = lstat4[tok];
            s_scores[it] = cvv; s_last[it] = tok;
            s_lmm[it] = st.x; s_lmls[it] = st.y;
            s_toks[t * BEAMW + it] = (unsigned short)tok;
            s_bps[t * BEAMW + it] = (unsigned char)bb;
          }
          pv = cvv; pi = cii;
        }
      }
    }
    __syncthreads();
  }

  if (tid < BEAMW) {
    out[tid] = s_scores[tid];
    int ptr = tid;
    for (int t = TT - 1; t >= 0; --t) {
      int tok = (int)s_toks[t * BEAMW + ptr];
      out[BEAMW + tid * TT + t] = (float)tok;
      ptr = (int)s_bps[t * BEAMW + ptr];
    }
  }
}

extern "C" void kernel_launch(void* const* d_in, const int* in_sizes, int n_in,
                              void* d_out, int out_size, void* d_ws, size_t ws_size,
                              hipStream_t stream) {
  const float* asr = (const float*)d_in[0];
  const float* lm  = (const float*)d_in[1];
  float* out = (float*)d_out;
  float* ws  = (float*)d_ws;

  int build = (ws_size >= ws_need_floats() * sizeof(float)) ? 1 : 0;
  hipLaunchKernelGGL(prep_kernel, dim3(VV + TT), dim3(256), 0, stream, asr, lm, ws, build);
  if (build)
    hipLaunchKernelGGL(beam_fast, dim3(1), dim3(1024), 0, stream, asr, lm, ws, out);
  else
    hipLaunchKernelGGL(beam_slow, dim3(1), dim3(1024), 0, stream, asr, lm, ws, out);
}

// Round 6
// 2463.494 us; speedup vs baseline: 1.4609x; 1.4609x over previous
//
#include <hip/hip_runtime.h>

#define TT 256
#define VV 5000
#define NC4 1250
#define BEAMW 16
#define WASR 0.7f
#define WLM 0.3f
#define SOS_TOK 1
#define LK 128          // list capacity (histogram-capped)
#define FCAP 512

// ws float offsets
#define OFF_LSTAT4 0                   // float4[VV] {m, logS, bsel_bits, lbnd}
#define OFF_AM     (4*VV)
#define OFF_ALS    (4*VV + TT)
#define OFF_ATH    (4*VV + 2*TT)       // bsel bits for asr rows (kept for completeness)
#define OFF_ABND   (4*VV + 3*TT)
#define OFF_COMM   (4*VV + 4*TT)       // 1024 uint words of communication
#define OFF_LISTS  (OFF_COMM + 1024)   // float2 L[VV][LK] then A[TT][LK]

// comm uint-word layout (relative to OFF_COMM):
//  [0..15]           fA[b]   survivor flags (tag)
//  [16]              fS      state flag (tag)
//  [32 + b*32 + 2k]  SURV_b: (valbits, flatidx) k=0..15
//  [544 + b]         BNDS[b] bound bits
//  [560 + 2i +{0,1}] STATE:  (scorebits, last)

static inline size_t ws_need_floats() {
  return (size_t)OFF_LISTS + 2ull * (VV + TT) * LK;
}

__device__ __forceinline__ int bin16(float m, float x) {
  float y   = __fsub_rn(m, x);
  float y16 = __fmul_rn(y, 16.0f);
  int bb = (int)y16;
  return bb < 0 ? 0 : (bb > 255 ? 255 : bb);
}

__device__ __forceinline__ unsigned int fkey(float v) {
  unsigned int u = __float_as_uint(v);
  return (u & 0x80000000u) ? ~u : (u | 0x80000000u);
}

__device__ __forceinline__ float cand_val(float s, float a, float am, float als,
                                          float x, float mB, float lsB) {
  float av = __fmul_rn(WASR, __fsub_rn(__fsub_rn(a, am), als));
  float lv = __fmul_rn(WLM,  __fsub_rn(__fsub_rn(x, mB), lsB));
  return __fadd_rn(__fadd_rn(s, av), lv);
}

__device__ __forceinline__ float bitonic64_desc_val(float v, int lane) {
#pragma unroll
  for (int kk = 2; kk <= 64; kk <<= 1)
#pragma unroll
    for (int j = kk >> 1; j > 0; j >>= 1) {
      float o = __shfl_xor(v, j, 64);
      bool keepMax = (((lane & kk) == 0) == ((lane & j) == 0));
      v = keepMax ? fmaxf(v, o) : fminf(v, o);
    }
  return v;
}

__device__ __forceinline__ void bitonic64_desc_pair(float& bv, int& bi, int lane) {
#pragma unroll
  for (int kk = 2; kk <= 64; kk <<= 1)
#pragma unroll
    for (int j = kk >> 1; j > 0; j >>= 1) {
      float ov = __shfl_xor(bv, j, 64);
      int   oi = __shfl_xor(bi, j, 64);
      bool keepTop = (((lane & kk) == 0) == ((lane & j) == 0));
      bool mineBetter = (bv > ov) || (bv == ov && bi < oi);
      if (keepTop != mineBetter) { bv = ov; bi = oi; }
    }
}

// ---------------- prep: row stats + θ-capped shortlists ----------
__global__ __launch_bounds__(256) void prep_kernel(
    const float* __restrict__ asr, const float* __restrict__ lm,
    float* __restrict__ ws, int build)
{
  __shared__ float sm[8];
  __shared__ int   hist[256];
  __shared__ int   s_bsel;
  __shared__ int   s_cnt;

  const int row = blockIdx.x;
  const bool is_lm = (row < VV);
  const int t = row - VV;
  const int tid = (int)threadIdx.x;

  if (row == 0) {
    for (int k = tid; k < 1024; k += 256)
      ((unsigned int*)(ws + OFF_COMM))[k] = 0u;
  }

  const float* src = is_lm ? (lm + (size_t)row * VV) : (asr + (size_t)t * VV);
  const float4* s4 = (const float4*)src;

  float4 x[5];
  float m = -INFINITY;
#pragma unroll
  for (int k = 0; k < 5; ++k) {
    int c = tid + 256 * k;
    if (c < NC4) {
      x[k] = s4[c];
      m = fmaxf(m, fmaxf(fmaxf(x[k].x, x[k].y), fmaxf(x[k].z, x[k].w)));
    }
  }
#pragma unroll
  for (int j = 1; j < 64; j <<= 1) m = fmaxf(m, __shfl_xor(m, j, 64));
  if ((tid & 63) == 0) sm[tid >> 6] = m;
  __syncthreads();
  m = fmaxf(fmaxf(sm[0], sm[1]), fmaxf(sm[2], sm[3]));
  __syncthreads();

  float ssum = 0.f;
#pragma unroll
  for (int k = 0; k < 5; ++k) {
    int c = tid + 256 * k;
    if (c < NC4) {
      ssum += expf(x[k].x - m);
      ssum += expf(x[k].y - m);
      ssum += expf(x[k].z - m);
      ssum += expf(x[k].w - m);
    }
  }
#pragma unroll
  for (int j = 1; j < 64; j <<= 1) ssum += __shfl_xor(ssum, j, 64);
  if ((tid & 63) == 0) sm[4 + (tid >> 6)] = ssum;
  __syncthreads();
  ssum = (sm[4] + sm[5]) + (sm[6] + sm[7]);
  const float logS = logf(ssum);

  if (!build) {
    if (tid == 0) {
      if (is_lm) ((float4*)(ws + OFF_LSTAT4))[row] = make_float4(m, logS, __int_as_float(0), 0.f);
      else { ws[OFF_AM + t] = m; ws[OFF_ALS + t] = logS; }
    }
    return;
  }
  if (!is_lm && tid == 0) { ws[OFF_AM + t] = m; ws[OFF_ALS + t] = logS; }

  hist[tid] = 0;
  __syncthreads();
#pragma unroll
  for (int k = 0; k < 5; ++k) {
    int c = tid + 256 * k;
    if (c < NC4) {
      float vv[4] = {x[k].x, x[k].y, x[k].z, x[k].w};
#pragma unroll
      for (int j = 0; j < 4; ++j) atomicAdd(&hist[bin16(m, vv[j])], 1);
    }
  }
  __syncthreads();
  if (tid == 0) {
    int c = 0, bsel = 0;
    for (; bsel < 256; ++bsel) {
      int nc = c + hist[bsel];
      if (nc <= LK) c = nc; else break;
    }
    s_bsel = bsel;   // bins [0, bsel) are listed; count c <= LK
    s_cnt = 0;
  }
  __syncthreads();
  const int bsel = s_bsel;
  const float wgt = is_lm ? WLM : WASR;
  float2* Llists = (float2*)(ws + OFF_LISTS);
  float2* dst = is_lm ? (Llists + (size_t)row * LK)
                      : (Llists + (size_t)VV * LK + (size_t)t * LK);
#pragma unroll
  for (int k = 0; k < 5; ++k) {
    int c = tid + 256 * k;
    if (c < NC4) {
      float vv[4] = {x[k].x, x[k].y, x[k].z, x[k].w};
#pragma unroll
      for (int j = 0; j < 4; ++j) {
        if (bin16(m, vv[j]) < bsel) {
          int p = atomicAdd(&s_cnt, 1);
          if (p < LK) {
            float sv = __fmul_rn(wgt, __fsub_rn(__fsub_rn(vv[j], m), logS));
            dst[p] = make_float2(sv, __int_as_float(c * 4 + j));
          }
        }
      }
    }
  }
  __syncthreads();
  const int cnt = s_cnt;
  const bool ovf = (cnt == 0);
  for (int p = cnt + tid; p < LK; p += 256)
    dst[p] = make_float2(-1e30f, __int_as_float(0x7FFFFFFF));

  if (tid == 0) {
    float theta = __fsub_rn(m, (float)bsel * 0.0625f);
    float bnd = ovf ? INFINITY : __fmul_rn(wgt, __fsub_rn(__fsub_rn(theta, m), logS));
    int bselO = ovf ? 0 : bsel;
    if (is_lm) ((float4*)(ws + OFF_LSTAT4))[row] = make_float4(m, logS, __int_as_float(bselO), bnd);
    else { ws[OFF_ATH + t] = __int_as_float(bselO); ws[OFF_ABND + t] = bnd; }
  }
}

// ---------------- multi-WG beam search: 16 WGs, one beam per CU ----------
__global__ __launch_bounds__(256) void beam_mw(
    const float* __restrict__ asr, const float* __restrict__ lm,
    float* __restrict__ ws, float* __restrict__ out)
{
  const int b   = (int)blockIdx.x;
  const int tid = (int)threadIdx.x;
  const int lane = tid & 63;
  const int w = tid >> 6;

  const float2* __restrict__ Llists = (const float2*)(ws + OFF_LISTS);
  const float2* __restrict__ Alists = Llists + (size_t)VV * LK;
  const float4* __restrict__ lstat4 = (const float4*)(ws + OFF_LSTAT4);
  unsigned int* C = (unsigned int*)(ws + OFF_COMM);

  __shared__ float s_cv[FCAP];
  __shared__ int   s_ct[FCAP];
  __shared__ unsigned long long s_key[256];
  __shared__ unsigned long long s_k2[64];
  __shared__ float s_sv2[64];
  __shared__ int   s_si2[64];
  __shared__ float s_selv[BEAMW];
  __shared__ int   s_seli[BEAMW];
  __shared__ float s_ftau[4];
  __shared__ int   s_fcnt;
  __shared__ int   s_redo;
  __shared__ unsigned int s_fsv;
  __shared__ float s_sc;
  __shared__ int   s_ls;
  __shared__ unsigned short s_toks[TT * BEAMW];   // WG0 only
  __shared__ unsigned char  s_bps[TT * BEAMW];    // WG0 only

  float s = (b == 0) ? 0.0f : -1e30f;
  int last = SOS_TOK;
  float4 lst = lstat4[SOS_TOK];

  for (int t = 0; t < TT; ++t) {
    const float am   = ws[OFF_AM + t];
    const float als  = ws[OFF_ALS + t];
    const float abnd = ws[OFF_ABND + t];
    const float mB = lst.x, lsB = lst.y, lbnd = lst.w;
    const int bselL = __float_as_int(lst.z);
    const float bound = __fadd_rn(__fadd_rn(s, abnd), lbnd) + 1e-3f;
    const unsigned tag1 = (unsigned)(2 * t + 1);
    const unsigned tag2 = (unsigned)(2 * t + 2);

    // ---- EVAL: 256 candidate slots (A: 0..127, L: 128..255) ----
    {
      float cv = -INFINITY; int ct = 0;
      int j = ((w & 1) << 6) | lane;
      if (w < 2) {
        float2 ae = Alists[(size_t)t * LK + j];
        int tok = __float_as_int(ae.y);
        bool valid = (ae.x > -9e29f);
        float xr = lm[(size_t)last * VV + (valid ? tok : 0)];
        if (valid) {
          ct = tok;
          bool inL = (bin16(mB, xr) < bselL);   // token also in L-list -> dedupe
          if (!inL) {
            float svr = __fmul_rn(WLM, __fsub_rn(__fsub_rn(xr, mB), lsB));
            cv = __fadd_rn(__fadd_rn(s, ae.x), svr);
          }
        }
      } else {
        float2 le = Llists[(size_t)last * LK + j];
        int tok = __float_as_int(le.y);
        bool valid = (le.x > -9e29f);
        float ar = asr[(size_t)t * VV + (valid ? tok : 0)];
        if (valid) {
          ct = tok;
          float avr = __fmul_rn(WASR, __fsub_rn(__fsub_rn(ar, am), als));
          cv = __fadd_rn(__fadd_rn(s, avr), le.x);
        }
      }
      s_cv[tid] = cv; s_ct[tid] = ct;
    }
    __syncthreads();

    // ---- per-beam exact top-16 of 256 (two-stage rank) ----
    {
      float v = s_cv[tid]; int tok = s_ct[tid];
      bool inval = !(v > -INFINITY);
      int tkk = inval ? (5000 + tid) : tok;
      unsigned long long key = ((unsigned long long)fkey(v) << 13) | (unsigned)(8191 - tkk);
      s_key[tid] = key;
      __syncthreads();
      int segbase = tid & ~63;
      int r = 0;
      for (int j = 0; j < 64; ++j) r += (s_key[segbase + j] > key) ? 1 : 0;
      if (r < BEAMW) {
        int slot = ((tid >> 6) << 4) | r;
        s_k2[slot] = key; s_sv2[slot] = v; s_si2[slot] = inval ? -1 : tok;
      }
      __syncthreads();
      if (tid < 64) {
        unsigned long long k2 = s_k2[tid];
        int r2 = 0;
        for (int j = 0; j < 64; ++j) r2 += (s_k2[j] > k2) ? 1 : 0;
        if (r2 < BEAMW) {
          int tk2 = s_si2[tid];
          s_selv[r2] = s_sv2[tid];
          s_seli[r2] = (tk2 < 0) ? (80000 + b * BEAMW + r2) : (b * VV + tk2);
        }
      }
      __syncthreads();
    }

    // ---- publish survivors (single-writer, release flag) ----
    if (tid == 0) {
      unsigned int* S = C + 32 + b * 32;
      for (int k = 0; k < BEAMW; ++k) {
        __hip_atomic_store(&S[2 * k], __float_as_uint(s_selv[k]), __ATOMIC_RELAXED, __HIP_MEMORY_SCOPE_AGENT);
        __hip_atomic_store(&S[2 * k + 1], (unsigned int)s_seli[k], __ATOMIC_RELAXED, __HIP_MEMORY_SCOPE_AGENT);
      }
      __hip_atomic_store(&C[544 + b], __float_as_uint(bound), __ATOMIC_RELAXED, __HIP_MEMORY_SCOPE_AGENT);
      __hip_atomic_store(&C[b], tag1, __ATOMIC_RELEASE, __HIP_MEMORY_SCOPE_AGENT);
    }

    // ---- WG0: merge + decide ----
    if (b == 0) {
      if (tid < BEAMW) {
        int gd = 0;
        while (__hip_atomic_load(&C[tid], __ATOMIC_ACQUIRE, __HIP_MEMORY_SCOPE_AGENT) < tag1) {
          __builtin_amdgcn_s_sleep(2);
          if (++gd > 4000000) break;
        }
      }
      __syncthreads();
      {
        int q = tid >> 4, r = tid & 15;
        const unsigned int* S = C + 32 + q * 32;
        unsigned vv = __hip_atomic_load(&S[2 * r], __ATOMIC_RELAXED, __HIP_MEMORY_SCOPE_AGENT);
        unsigned ff = __hip_atomic_load(&S[2 * r + 1], __ATOMIC_RELAXED, __HIP_MEMORY_SCOPE_AGENT);
        s_cv[tid] = __uint_as_float(vv);
        s_ct[tid] = (int)ff;
      }
      __syncthreads();
      {
        float v = s_cv[tid]; int fl = s_ct[tid];
        unsigned long long key = ((unsigned long long)fkey(v) << 17) | (unsigned)(131071 - fl);
        s_key[tid] = key;
        __syncthreads();
        int segbase = tid & ~63;
        int r = 0;
        for (int j = 0; j < 64; ++j) r += (s_key[segbase + j] > key) ? 1 : 0;
        if (r < BEAMW) {
          int slot = ((tid >> 6) << 4) | r;
          s_k2[slot] = key; s_sv2[slot] = v; s_si2[slot] = fl;
        }
        __syncthreads();
        if (tid < 64) {
          unsigned long long k2 = s_k2[tid];
          int r2 = 0;
          for (int j = 0; j < 64; ++j) r2 += (s_k2[j] > k2) ? 1 : 0;
          if (r2 < BEAMW) { s_selv[r2] = s_sv2[tid]; s_seli[r2] = s_si2[tid]; }
        }
        __syncthreads();
      }
      {
        float tau16 = s_selv[BEAMW - 1];
        bool c16 = false;
        if (tid < BEAMW) {
          float bq = __uint_as_float(__hip_atomic_load(&C[544 + tid], __ATOMIC_RELAXED, __HIP_MEMORY_SCOPE_AGENT));
          c16 = (bq > tau16);
        }
        unsigned long long mk = __ballot(c16);
        if (tid == 0) s_redo = (mk != 0ull) ? 1 : 0;
      }
      __syncthreads();
      if (s_redo) {
        if (tid == 0)
          __hip_atomic_store(&C[16], tag1, __ATOMIC_RELEASE, __HIP_MEMORY_SCOPE_AGENT);
      } else {
        // commit history + publish state
        if (tid < BEAMW) {
          int fl = s_seli[tid];
          int bp = fl / VV; int tok = fl - bp * VV;
          s_toks[t * BEAMW + tid] = (unsigned short)tok;
          s_bps[t * BEAMW + tid]  = (unsigned char)bp;
        }
        if (tid == 0) {
          for (int i = 0; i < BEAMW; ++i) {
            int fl = s_seli[i]; int bp = fl / VV; int tok = fl - bp * VV;
            __hip_atomic_store(&C[560 + 2 * i], __float_as_uint(s_selv[i]), __ATOMIC_RELAXED, __HIP_MEMORY_SCOPE_AGENT);
            __hip_atomic_store(&C[560 + 2 * i + 1], (unsigned int)tok, __ATOMIC_RELAXED, __HIP_MEMORY_SCOPE_AGENT);
          }
          __hip_atomic_store(&C[16], tag2, __ATOMIC_RELEASE, __HIP_MEMORY_SCOPE_AGENT);
        }
      }
      __syncthreads();
    } else {
      // observe redo-vs-done
      if (tid == 0) {
        int gd = 0;
        unsigned v;
        for (;;) {
          v = __hip_atomic_load(&C[16], __ATOMIC_ACQUIRE, __HIP_MEMORY_SCOPE_AGENT);
          if (v >= tag1) break;
          __builtin_amdgcn_s_sleep(2);
          if (++gd > 4000000) { v = tag2; break; }
        }
        s_fsv = v;
        s_redo = (v == tag1) ? 1 : 0;
      }
      __syncthreads();
    }

    // ---- rare: exact per-beam full-scan fallback ----
    if (s_redo) {
      if (tid == 0) s_fcnt = 0;
      const float4* A4 = (const float4*)(asr + (size_t)t * VV);
      const float4* L4 = (const float4*)(lm + (size_t)last * VV);
      float chm[5]; float tm = -INFINITY;
#pragma unroll
      for (int q = 0; q < 5; ++q) {
        int c = tid + (q << 8);
        float cm = -INFINITY;
        if (c < NC4) {
          float4 a4 = A4[c]; float4 l4 = L4[c];
          float v0 = cand_val(s, a4.x, am, als, l4.x, mB, lsB);
          float v1 = cand_val(s, a4.y, am, als, l4.y, mB, lsB);
          float v2 = cand_val(s, a4.z, am, als, l4.z, mB, lsB);
          float v3 = cand_val(s, a4.w, am, als, l4.w, mB, lsB);
          cm = fmaxf(fmaxf(v0, v1), fmaxf(v2, v3));
        }
        chm[q] = cm; tm = fmaxf(tm, cm);
      }
      float vs = bitonic64_desc_val(tm, lane);
      if (lane == 15) s_ftau[w] = vs;
      __syncthreads();
      float tg = fmaxf(fmaxf(s_ftau[0], s_ftau[1]), fmaxf(s_ftau[2], s_ftau[3]));
#pragma unroll
      for (int q = 0; q < 5; ++q) {
        if (chm[q] >= tg) {
          int c = tid + (q << 8);
          float4 a4 = A4[c]; float4 l4 = L4[c];
          float ar4[4] = {a4.x, a4.y, a4.z, a4.w};
          float lr4[4] = {l4.x, l4.y, l4.z, l4.w};
#pragma unroll
          for (int i = 0; i < 4; ++i) {
            float v = cand_val(s, ar4[i], am, als, lr4[i], mB, lsB);
            if (v >= tg) {
              int p = atomicAdd(&s_fcnt, 1);
              if (p < FCAP) { s_cv[p] = v; s_ct[p] = c * 4 + i; }
            }
          }
        }
      }
      __syncthreads();
      int n = s_fcnt; if (n > FCAP) n = FCAP;
      {
        float v0 = (tid < n) ? s_cv[tid] : -INFINITY;
        int   t0 = (tid < n) ? s_ct[tid] : 0;
        float v1 = (tid + 256 < n) ? s_cv[tid + 256] : -INFINITY;
        int   t1 = (tid + 256 < n) ? s_ct[tid + 256] : 0;
        unsigned long long k0 = ((unsigned long long)fkey(v0) << 13) | (unsigned)(8191 - t0);
        unsigned long long k1 = ((unsigned long long)fkey(v1) << 13) | (unsigned)(8191 - t1);
        int r0 = 0, r1 = 0;
        for (int j = 0; j < n; ++j) {
          unsigned long long kj = ((unsigned long long)fkey(s_cv[j]) << 13) | (unsigned)(8191 - s_ct[j]);
          r0 += (kj > k0) ? 1 : 0;
          r1 += (kj > k1) ? 1 : 0;
        }
        if (tid < n && r0 < BEAMW)       { s_selv[r0] = v0; s_seli[r0] = b * VV + t0; }
        if (tid + 256 < n && r1 < BEAMW) { s_selv[r1] = v1; s_seli[r1] = b * VV + t1; }
      }
      __syncthreads();

      // republish with tag2
      if (tid == 0) {
        unsigned int* S = C + 32 + b * 32;
        for (int k = 0; k < BEAMW; ++k) {
          __hip_atomic_store(&S[2 * k], __float_as_uint(s_selv[k]), __ATOMIC_RELAXED, __HIP_MEMORY_SCOPE_AGENT);
          __hip_atomic_store(&S[2 * k + 1], (unsigned int)s_seli[k], __ATOMIC_RELAXED, __HIP_MEMORY_SCOPE_AGENT);
        }
        __hip_atomic_store(&C[b], tag2, __ATOMIC_RELEASE, __HIP_MEMORY_SCOPE_AGENT);
      }

      if (b == 0) {
        if (tid < BEAMW) {
          int gd = 0;
          while (__hip_atomic_load(&C[tid], __ATOMIC_ACQUIRE, __HIP_MEMORY_SCOPE_AGENT) < tag2) {
            __builtin_amdgcn_s_sleep(2);
            if (++gd > 4000000) break;
          }
        }
        __syncthreads();
        {
          int q = tid >> 4, r = tid & 15;
          const unsigned int* S = C + 32 + q * 32;
          unsigned vv = __hip_atomic_load(&S[2 * r], __ATOMIC_RELAXED, __HIP_MEMORY_SCOPE_AGENT);
          unsigned ff = __hip_atomic_load(&S[2 * r + 1], __ATOMIC_RELAXED, __HIP_MEMORY_SCOPE_AGENT);
          s_cv[tid] = __uint_as_float(vv);
          s_ct[tid] = (int)ff;
        }
        __syncthreads();
        {
          float v = s_cv[tid]; int fl = s_ct[tid];
          unsigned long long key = ((unsigned long long)fkey(v) << 17) | (unsigned)(131071 - fl);
          s_key[tid] = key;
          __syncthreads();
          int segbase = tid & ~63;
          int r = 0;
          for (int j = 0; j < 64; ++j) r += (s_key[segbase + j] > key) ? 1 : 0;
          if (r < BEAMW) {
            int slot = ((tid >> 6) << 4) | r;
            s_k2[slot] = key; s_sv2[slot] = v; s_si2[slot] = fl;
          }
          __syncthreads();
          if (tid < 64) {
            unsigned long long k2 = s_k2[tid];
            int r2 = 0;
            for (int j = 0; j < 64; ++j) r2 += (s_k2[j] > k2) ? 1 : 0;
            if (r2 < BEAMW) { s_selv[r2] = s_sv2[tid]; s_seli[r2] = s_si2[tid]; }
          }
          __syncthreads();
        }
        if (tid < BEAMW) {
          int fl = s_seli[tid];
          int bp = fl / VV; int tok = fl - bp * VV;
          s_toks[t * BEAMW + tid] = (unsigned short)tok;
          s_bps[t * BEAMW + tid]  = (unsigned char)bp;
        }
        if (tid == 0) {
          for (int i = 0; i < BEAMW; ++i) {
            int fl = s_seli[i]; int bp = fl / VV; int tok = fl - bp * VV;
            __hip_atomic_store(&C[560 + 2 * i], __float_as_uint(s_selv[i]), __ATOMIC_RELAXED, __HIP_MEMORY_SCOPE_AGENT);
            __hip_atomic_store(&C[560 + 2 * i + 1], (unsigned int)tok, __ATOMIC_RELAXED, __HIP_MEMORY_SCOPE_AGENT);
          }
          __hip_atomic_store(&C[16], tag2, __ATOMIC_RELEASE, __HIP_MEMORY_SCOPE_AGENT);
        }
        __syncthreads();
      }
    }

    // ---- read next state ----
    if (t < TT - 1) {
      if (tid == 0) {
        int gd = 0;
        while (__hip_atomic_load(&C[16], __ATOMIC_ACQUIRE, __HIP_MEMORY_SCOPE_AGENT) < tag2) {
          __builtin_amdgcn_s_sleep(2);
          if (++gd > 4000000) break;
        }
        unsigned sv = __hip_atomic_load(&C[560 + 2 * b], __ATOMIC_RELAXED, __HIP_MEMORY_SCOPE_AGENT);
        unsigned lv = __hip_atomic_load(&C[560 + 2 * b + 1], __ATOMIC_RELAXED, __HIP_MEMORY_SCOPE_AGENT);
        s_sc = __uint_as_float(sv);
        s_ls = (int)lv;
      }
      __syncthreads();
      s = s_sc; last = s_ls;
      lst = lstat4[last];
      __syncthreads();
    }
  }

  // ---- output (WG0) ----
  if (b == 0) {
    if (tid < BEAMW) {
      out[tid] = s_selv[tid];
      int ptr = tid;
      for (int tt = TT - 1; tt >= 0; --tt) {
        int tok = (int)s_toks[tt * BEAMW + ptr];
        out[BEAMW + tid * TT + tt] = (float)tok;
        ptr = (int)s_bps[tt * BEAMW + ptr];
      }
    }
  }
}

// ---------------- fallback: single-WG full-scan kernel (ws too small) ----
__global__ __launch_bounds__(1024, 4) void beam_slow(
    const float* __restrict__ asr, const float* __restrict__ lm,
    const float* __restrict__ ws, float* __restrict__ out)
{
  __shared__ float s_scores[BEAMW];
  __shared__ int   s_last[BEAMW];
  __shared__ float s_lmm[BEAMW], s_lmls[BEAMW];
  __shared__ float s_tau[BEAMW];
  __shared__ float s_bufval[FCAP];
  __shared__ int   s_bufidx[FCAP];
  __shared__ int   s_cnt;
  __shared__ unsigned short s_toks[TT * BEAMW];
  __shared__ unsigned char  s_bps[TT * BEAMW];

  const int tid = (int)threadIdx.x;
  const int lane = tid & 63;
  const int w = tid >> 6;
  const float4* __restrict__ lstat4 = (const float4*)(ws + OFF_LSTAT4);

  if (tid < BEAMW) {
    s_scores[tid] = (tid == 0) ? 0.0f : -1e30f;
    s_last[tid] = SOS_TOK;
    float4 st = lstat4[SOS_TOK];
    s_lmm[tid] = st.x; s_lmls[tid] = st.y;
  }
  if (tid == 0) s_cnt = 0;
  __syncthreads();

  for (int t = 0; t < TT; ++t) {
    const float s = s_scores[w];
    const float mB = s_lmm[w], lsB = s_lmls[w];
    const int lastb = s_last[w];
    const float am = ws[OFF_AM + t], als = ws[OFF_ALS + t];
    const float4* __restrict__ L4p = (const float4*)(lm + (size_t)lastb * VV);
    const float4* __restrict__ A4p = (const float4*)(asr + (size_t)t * VV);

    float chm[20]; float rowm = -INFINITY;
#pragma unroll
    for (int k = 0; k < 20; ++k) {
      int c = lane + 64 * k;
      bool ok = (c < NC4);
      int cc = ok ? c : 0;
      float4 A4 = A4p[cc]; float4 L4 = L4p[cc];
      float vx = cand_val(s, A4.x, am, als, L4.x, mB, lsB);
      float vy = cand_val(s, A4.y, am, als, L4.y, mB, lsB);
      float vz = cand_val(s, A4.z, am, als, L4.z, mB, lsB);
      float vw = cand_val(s, A4.w, am, als, L4.w, mB, lsB);
      float cm = fmaxf(fmaxf(vx, vy), fmaxf(vz, vw));
      if (!ok) cm = -INFINITY;
      chm[k] = cm; rowm = fmaxf(rowm, cm);
    }
    {
      float v = bitonic64_desc_val(rowm, lane);
      if (lane == 15) s_tau[w] = v;
    }
    if (tid == 0) s_cnt = 0;
    __syncthreads();

    float tg = s_tau[lane & 15];
#pragma unroll
    for (int j = 1; j <= 8; j <<= 1) tg = fmaxf(tg, __shfl_xor(tg, j, 64));

#pragma unroll
    for (int k = 0; k < 20; ++k) {
      if (chm[k] >= tg) {
        int c = lane + 64 * k;
        float4 A4 = A4p[c]; float4 L4 = L4p[c];
        float ar4[4] = {A4.x, A4.y, A4.z, A4.w};
        float lr4[4] = {L4.x, L4.y, L4.z, L4.w};
#pragma unroll
        for (int i = 0; i < 4; ++i) {
          float v = cand_val(s, ar4[i], am, als, lr4[i], mB, lsB);
          if (v >= tg) {
            int p = atomicAdd(&s_cnt, 1);
            if (p < FCAP) { s_bufval[p] = v; s_bufidx[p] = w * VV + c * 4 + i; }
          }
        }
      }
    }
    __syncthreads();

    if (w == 0) {
      int n = s_cnt; if (n > FCAP) n = FCAP;
      if (n <= 64) {
        float bv = (lane < n) ? s_bufval[lane] : -INFINITY;
        int   bi = (lane < n) ? s_bufidx[lane] : 0x7FFFFFFF;
        bitonic64_desc_pair(bv, bi, lane);
        if (lane < BEAMW) {
          int flat = bi;
          int bb = flat / VV; int tok = flat - bb * VV;
          float4 st = lstat4[tok];
          s_scores[lane] = bv; s_last[lane] = tok;
          s_lmm[lane] = st.x; s_lmls[lane] = st.y;
          s_toks[t * BEAMW + lane] = (unsigned short)tok;
          s_bps[t * BEAMW + lane] = (unsigned char)bb;
        }
      } else {
        float pv = -INFINITY; int pi = 0x7FFFFFFF;
        for (int it = 0; it < BEAMW; ++it) {
          float cvv = -INFINITY; int cii = 0x7FFFFFFF;
          for (int k2 = 0; k2 < FCAP / 64; ++k2) {
            int p = lane + 64 * k2;
            if (p < n) {
              float vv2 = s_bufval[p]; int ii2 = s_bufidx[p];
              bool lessPrev = (it == 0) || (vv2 < pv) || (vv2 == pv && ii2 > pi);
              bool better = (vv2 > cvv) || (vv2 == cvv && ii2 < cii);
              if (lessPrev && better) { cvv = vv2; cii = ii2; }
            }
          }
          for (int j = 1; j < 64; j <<= 1) {
            float ov = __shfl_xor(cvv, j, 64); int oi = __shfl_xor(cii, j, 64);
            bool ob = (ov > cvv) || (ov == cvv && oi < cii);
            if (ob) { cvv = ov; cii = oi; }
          }
          if (lane == 0) {
            int bb = cii / VV; int tok = cii - bb * VV;
            float4 st = lstat4[tok];
            s_scores[it] = cvv; s_last[it] = tok;
            s_lmm[it] = st.x; s_lmls[it] = st.y;
            s_toks[t * BEAMW + it] = (unsigned short)tok;
            s_bps[t * BEAMW + it] = (unsigned char)bb;
          }
          pv = cvv; pi = cii;
        }
      }
    }
    __syncthreads();
  }

  if (tid < BEAMW) {
    out[tid] = s_scores[tid];
    int ptr = tid;
    for (int t = TT - 1; t >= 0; --t) {
      int tok = (int)s_toks[t * BEAMW + ptr];
      out[BEAMW + tid * TT + t] = (float)tok;
      ptr = (int)s_bps[t * BEAMW + ptr];
    }
  }
}

extern "C" void kernel_launch(void* const* d_in, const int* in_sizes, int n_in,
                              void* d_out, int out_size, void* d_ws, size_t ws_size,
                              hipStream_t stream) {
  const float* asr = (const float*)d_in[0];
  const float* lm  = (const float*)d_in[1];
  float* out = (float*)d_out;
  float* ws  = (float*)d_ws;

  int build = (ws_size >= ws_need_floats() * sizeof(float)) ? 1 : 0;
  hipLaunchKernelGGL(prep_kernel, dim3(VV + TT), dim3(256), 0, stream, asr, lm, ws, build);
  if (build)
    hipLaunchKernelGGL(beam_mw, dim3(BEAMW), dim3(256), 0, stream, asr, lm, ws, out);
  else
    hipLaunchKernelGGL(beam_slow, dim3(1), dim3(1024), 0, stream, asr, lm, ws, out);
}

// Round 7
// 1683.820 us; speedup vs baseline: 2.1374x; 1.4630x over previous
//
#include <hip/hip_runtime.h>

#define TT 256
#define VV 5000
#define NC4 1250
#define BEAMW 16
#define WASR 0.7f
#define WLM 0.3f
#define SOS_TOK 1
#define LK 128          // list capacity (histogram-capped)
#define FCAP 512
#define COMMW 2048

// ws float offsets
#define OFF_LSTAT4 0                   // float4[VV] {m, logS, bsel_bits, lbnd}
#define OFF_AM     (4*VV)
#define OFF_ALS    (4*VV + TT)
#define OFF_ATH    (4*VV + 2*TT)
#define OFF_ABND   (4*VV + 3*TT)
#define OFF_COMM   (4*VV + 4*TT)       // COMMW uint words
#define OFF_LISTS  (OFF_COMM + COMMW)  // float2 L[VV][LK] then A[TT][LK]

// comm uint-word layout (relative to OFF_COMM):
//  [17]              phase-1 counter (16 per step)
//  [18]              redo counter (16 per redo epoch)
//  [32 + b*32 + 2k]  SURV_b phase-1: ull pair (val | flat<<32), k=0..15
//  [544 + b]         BNDS[b] bound bits
//  [592 + b*32 + 2k] SURV_b redo: ull pairs
static inline size_t ws_need_floats() {
  return (size_t)OFF_LISTS + 2ull * (VV + TT) * LK;
}

__device__ __forceinline__ int bin16(float m, float x) {
  float y   = __fsub_rn(m, x);
  float y16 = __fmul_rn(y, 16.0f);
  int bb = (int)y16;
  return bb < 0 ? 0 : (bb > 255 ? 255 : bb);
}

__device__ __forceinline__ unsigned int fkey(float v) {
  unsigned int u = __float_as_uint(v);
  return (u & 0x80000000u) ? ~u : (u | 0x80000000u);
}

__device__ __forceinline__ float cand_val(float s, float a, float am, float als,
                                          float x, float mB, float lsB) {
  float av = __fmul_rn(WASR, __fsub_rn(__fsub_rn(a, am), als));
  float lv = __fmul_rn(WLM,  __fsub_rn(__fsub_rn(x, mB), lsB));
  return __fadd_rn(__fadd_rn(s, av), lv);
}

__device__ __forceinline__ float bitonic64_desc_val(float v, int lane) {
#pragma unroll
  for (int kk = 2; kk <= 64; kk <<= 1)
#pragma unroll
    for (int j = kk >> 1; j > 0; j >>= 1) {
      float o = __shfl_xor(v, j, 64);
      bool keepMax = (((lane & kk) == 0) == ((lane & j) == 0));
      v = keepMax ? fmaxf(v, o) : fminf(v, o);
    }
  return v;
}

__device__ __forceinline__ void bitonic64_desc_pair(float& bv, int& bi, int lane) {
#pragma unroll
  for (int kk = 2; kk <= 64; kk <<= 1)
#pragma unroll
    for (int j = kk >> 1; j > 0; j >>= 1) {
      float ov = __shfl_xor(bv, j, 64);
      int   oi = __shfl_xor(bi, j, 64);
      bool keepTop = (((lane & kk) == 0) == ((lane & j) == 0));
      bool mineBetter = (bv > ov) || (bv == ov && bi < oi);
      if (keepTop != mineBetter) { bv = ov; bi = oi; }
    }
}

// ---------------- prep: row stats + θ-capped shortlists ----------
__global__ __launch_bounds__(256) void prep_kernel(
    const float* __restrict__ asr, const float* __restrict__ lm,
    float* __restrict__ ws, int build)
{
  __shared__ float sm[8];
  __shared__ int   hist[256];
  __shared__ int   s_bsel;
  __shared__ int   s_cnt;

  const int row = blockIdx.x;
  const bool is_lm = (row < VV);
  const int t = row - VV;
  const int tid = (int)threadIdx.x;

  if (row == 0) {
    for (int k = tid; k < COMMW; k += 256)
      ((unsigned int*)(ws + OFF_COMM))[k] = 0u;
  }

  const float* src = is_lm ? (lm + (size_t)row * VV) : (asr + (size_t)t * VV);
  const float4* s4 = (const float4*)src;

  float4 x[5];
  float m = -INFINITY;
#pragma unroll
  for (int k = 0; k < 5; ++k) {
    int c = tid + 256 * k;
    if (c < NC4) {
      x[k] = s4[c];
      m = fmaxf(m, fmaxf(fmaxf(x[k].x, x[k].y), fmaxf(x[k].z, x[k].w)));
    }
  }
#pragma unroll
  for (int j = 1; j < 64; j <<= 1) m = fmaxf(m, __shfl_xor(m, j, 64));
  if ((tid & 63) == 0) sm[tid >> 6] = m;
  __syncthreads();
  m = fmaxf(fmaxf(sm[0], sm[1]), fmaxf(sm[2], sm[3]));
  __syncthreads();

  float ssum = 0.f;
#pragma unroll
  for (int k = 0; k < 5; ++k) {
    int c = tid + 256 * k;
    if (c < NC4) {
      ssum += expf(x[k].x - m);
      ssum += expf(x[k].y - m);
      ssum += expf(x[k].z - m);
      ssum += expf(x[k].w - m);
    }
  }
#pragma unroll
  for (int j = 1; j < 64; j <<= 1) ssum += __shfl_xor(ssum, j, 64);
  if ((tid & 63) == 0) sm[4 + (tid >> 6)] = ssum;
  __syncthreads();
  ssum = (sm[4] + sm[5]) + (sm[6] + sm[7]);
  const float logS = logf(ssum);

  if (!build) {
    if (tid == 0) {
      if (is_lm) ((float4*)(ws + OFF_LSTAT4))[row] = make_float4(m, logS, __int_as_float(0), 0.f);
      else { ws[OFF_AM + t] = m; ws[OFF_ALS + t] = logS; }
    }
    return;
  }
  if (!is_lm && tid == 0) { ws[OFF_AM + t] = m; ws[OFF_ALS + t] = logS; }

  hist[tid] = 0;
  __syncthreads();
#pragma unroll
  for (int k = 0; k < 5; ++k) {
    int c = tid + 256 * k;
    if (c < NC4) {
      float vv[4] = {x[k].x, x[k].y, x[k].z, x[k].w};
#pragma unroll
      for (int j = 0; j < 4; ++j) atomicAdd(&hist[bin16(m, vv[j])], 1);
    }
  }
  __syncthreads();
  if (tid == 0) {
    int c = 0, bsel = 0;
    for (; bsel < 256; ++bsel) {
      int nc = c + hist[bsel];
      if (nc <= LK) c = nc; else break;
    }
    s_bsel = bsel;
    s_cnt = 0;
  }
  __syncthreads();
  const int bsel = s_bsel;
  const float wgt = is_lm ? WLM : WASR;
  float2* Llists = (float2*)(ws + OFF_LISTS);
  float2* dst = is_lm ? (Llists + (size_t)row * LK)
                      : (Llists + (size_t)VV * LK + (size_t)t * LK);
#pragma unroll
  for (int k = 0; k < 5; ++k) {
    int c = tid + 256 * k;
    if (c < NC4) {
      float vv[4] = {x[k].x, x[k].y, x[k].z, x[k].w};
#pragma unroll
      for (int j = 0; j < 4; ++j) {
        if (bin16(m, vv[j]) < bsel) {
          int p = atomicAdd(&s_cnt, 1);
          if (p < LK) {
            float sv = __fmul_rn(wgt, __fsub_rn(__fsub_rn(vv[j], m), logS));
            dst[p] = make_float2(sv, __int_as_float(c * 4 + j));
          }
        }
      }
    }
  }
  __syncthreads();
  const int cnt = s_cnt;
  const bool ovf = (cnt == 0);
  for (int p = cnt + tid; p < LK; p += 256)
    dst[p] = make_float2(-1e30f, __int_as_float(0x7FFFFFFF));

  if (tid == 0) {
    float theta = __fsub_rn(m, (float)bsel * 0.0625f);
    float bnd = ovf ? INFINITY : __fmul_rn(wgt, __fsub_rn(__fsub_rn(theta, m), logS));
    int bselO = ovf ? 0 : bsel;
    if (is_lm) ((float4*)(ws + OFF_LSTAT4))[row] = make_float4(m, logS, __int_as_float(bselO), bnd);
    else { ws[OFF_ATH + t] = __int_as_float(bselO); ws[OFF_ABND + t] = bnd; }
  }
}

// ---------------- multi-WG beam search: 16 WGs, one counter barrier/step ----------
__global__ __launch_bounds__(256) void beam_mw(
    const float* __restrict__ asr, const float* __restrict__ lm,
    float* __restrict__ ws, float* __restrict__ out)
{
  const int b   = (int)blockIdx.x;
  const int tid = (int)threadIdx.x;
  const int lane = tid & 63;
  const int w = tid >> 6;

  const float2* __restrict__ Llists = (const float2*)(ws + OFF_LISTS);
  const float2* __restrict__ Alists = Llists + (size_t)VV * LK;
  const float4* __restrict__ lstat4 = (const float4*)(ws + OFF_LSTAT4);
  unsigned int* C = (unsigned int*)(ws + OFF_COMM);

  __shared__ float s_cv[FCAP];
  __shared__ int   s_ct[FCAP];
  __shared__ unsigned long long s_key[256];
  __shared__ unsigned long long s_k2[64];
  __shared__ float s_sv2[64];
  __shared__ int   s_si2[64];
  __shared__ float s_selv[BEAMW];
  __shared__ int   s_seli[BEAMW];
  __shared__ float s_ftau[4];
  __shared__ int   s_fcnt;
  __shared__ int   s_redo;
  __shared__ unsigned short s_toks[TT * BEAMW];   // WG0 only
  __shared__ unsigned char  s_bps[TT * BEAMW];    // WG0 only

  float s = (b == 0) ? 0.0f : -1e30f;
  int last = SOS_TOK;
  float4 lst = lstat4[SOS_TOK];
  int redo_epoch = 0;

  // local merge of 256 pooled survivors (s_cv/s_ct) -> s_selv/s_seli (all WGs)
  auto merge256 = [&]() {
    float v = s_cv[tid]; int fl = s_ct[tid];
    unsigned long long key = ((unsigned long long)fkey(v) << 17) | (unsigned)(131071 - fl);
    s_key[tid] = key;
    __syncthreads();
    int segbase = tid & ~63;
    int r = 0;
    for (int j = 0; j < 64; ++j) r += (s_key[segbase + j] > key) ? 1 : 0;
    if (r < BEAMW) {
      int slot = ((tid >> 6) << 4) | r;
      s_k2[slot] = key; s_sv2[slot] = v; s_si2[slot] = fl;
    }
    __syncthreads();
    if (tid < 64) {
      unsigned long long k2 = s_k2[tid];
      int r2 = 0;
      for (int j = 0; j < 64; ++j) r2 += (s_k2[j] > k2) ? 1 : 0;
      if (r2 < BEAMW) { s_selv[r2] = s_sv2[tid]; s_seli[r2] = s_si2[tid]; }
    }
    __syncthreads();
  };

  for (int t = 0; t < TT; ++t) {
    const float am   = ws[OFF_AM + t];
    const float als  = ws[OFF_ALS + t];
    const float abnd = ws[OFF_ABND + t];
    const float mB = lst.x, lsB = lst.y, lbnd = lst.w;
    const int bselL = __float_as_int(lst.z);
    const float bound = __fadd_rn(__fadd_rn(s, abnd), lbnd) + 1e-3f;

    // ---- EVAL: 256 candidate slots (A: 0..127, L: 128..255) ----
    {
      float cv = -INFINITY; int ct = 0;
      int j = ((w & 1) << 6) | lane;
      if (w < 2) {
        float2 ae = Alists[(size_t)t * LK + j];
        int tok = __float_as_int(ae.y);
        bool valid = (ae.x > -9e29f);
        float xr = lm[(size_t)last * VV + (valid ? tok : 0)];
        if (valid) {
          ct = tok;
          bool inL = (bin16(mB, xr) < bselL);   // dedupe: token also in L-list
          if (!inL) {
            float svr = __fmul_rn(WLM, __fsub_rn(__fsub_rn(xr, mB), lsB));
            cv = __fadd_rn(__fadd_rn(s, ae.x), svr);
          }
        }
      } else {
        float2 le = Llists[(size_t)last * LK + j];
        int tok = __float_as_int(le.y);
        bool valid = (le.x > -9e29f);
        float ar = asr[(size_t)t * VV + (valid ? tok : 0)];
        if (valid) {
          ct = tok;
          float avr = __fmul_rn(WASR, __fsub_rn(__fsub_rn(ar, am), als));
          cv = __fadd_rn(__fadd_rn(s, avr), le.x);
        }
      }
      s_cv[tid] = cv; s_ct[tid] = ct;
    }
    __syncthreads();

    // ---- per-beam exact top-16 of 256 (two-stage rank) ----
    {
      float v = s_cv[tid]; int tok = s_ct[tid];
      bool inval = !(v > -INFINITY);
      int tkk = inval ? (5000 + tid) : tok;
      unsigned long long key = ((unsigned long long)fkey(v) << 13) | (unsigned)(8191 - tkk);
      s_key[tid] = key;
      __syncthreads();
      int segbase = tid & ~63;
      int r = 0;
      for (int j = 0; j < 64; ++j) r += (s_key[segbase + j] > key) ? 1 : 0;
      if (r < BEAMW) {
        int slot = ((tid >> 6) << 4) | r;
        s_k2[slot] = key; s_sv2[slot] = v; s_si2[slot] = inval ? -1 : tok;
      }
      __syncthreads();
      if (tid < 64) {
        unsigned long long k2 = s_k2[tid];
        int r2 = 0;
        for (int j = 0; j < 64; ++j) r2 += (s_k2[j] > k2) ? 1 : 0;
        if (r2 < BEAMW) {
          int tk2 = s_si2[tid];
          s_selv[r2] = s_sv2[tid];
          s_seli[r2] = (tk2 < 0) ? (80000 + b * BEAMW + r2) : (b * VV + tk2);
        }
      }
      __syncthreads();
    }

    // ---- publish 16 pairs + bound; release counter-add; acquire poll ----
    if (tid == 0) {
      unsigned long long* S = (unsigned long long*)(C + 32 + b * 32);
      for (int k = 0; k < BEAMW; ++k) {
        unsigned long long pk = ((unsigned long long)(unsigned int)s_seli[k] << 32)
                              | (unsigned long long)__float_as_uint(s_selv[k]);
        __hip_atomic_store(&S[k], pk, __ATOMIC_RELAXED, __HIP_MEMORY_SCOPE_AGENT);
      }
      __hip_atomic_store(&C[544 + b], __float_as_uint(bound), __ATOMIC_RELAXED, __HIP_MEMORY_SCOPE_AGENT);
      __hip_atomic_fetch_add(&C[17], 1u, __ATOMIC_RELEASE, __HIP_MEMORY_SCOPE_AGENT);
      int gd = 0;
      while (__hip_atomic_load(&C[17], __ATOMIC_ACQUIRE, __HIP_MEMORY_SCOPE_AGENT) < (unsigned)(BEAMW * (t + 1))) {
        __builtin_amdgcn_s_sleep(2);
        if (++gd > 4000000) break;
      }
    }
    __syncthreads();

    // ---- read all 256 survivors; local redundant merge ----
    {
      const unsigned long long* S = (const unsigned long long*)(C + 32 + (tid >> 4) * 32);
      unsigned long long pk = __hip_atomic_load(&S[tid & 15], __ATOMIC_RELAXED, __HIP_MEMORY_SCOPE_AGENT);
      s_cv[tid] = __uint_as_float((unsigned int)pk);
      s_ct[tid] = (int)(unsigned int)(pk >> 32);
    }
    __syncthreads();
    merge256();

    // ---- redundant redo decision ----
    {
      float tau16 = s_selv[BEAMW - 1];
      bool c16 = false;
      if (tid < BEAMW) {
        float bq = __uint_as_float(__hip_atomic_load(&C[544 + tid], __ATOMIC_RELAXED, __HIP_MEMORY_SCOPE_AGENT));
        c16 = (bq > tau16);
      }
      unsigned long long mk = __ballot(c16);
      if (tid == 0) s_redo = (mk != 0ull) ? 1 : 0;
    }
    __syncthreads();

    // ---- rare: exact per-beam full scan + re-merge via redo buffer ----
    if (s_redo) {
      redo_epoch++;
      if (tid == 0) s_fcnt = 0;
      const float4* A4 = (const float4*)(asr + (size_t)t * VV);
      const float4* L4 = (const float4*)(lm + (size_t)last * VV);
      float chm[5]; float tm = -INFINITY;
#pragma unroll
      for (int q = 0; q < 5; ++q) {
        int c = tid + (q << 8);
        float cm = -INFINITY;
        if (c < NC4) {
          float4 a4 = A4[c]; float4 l4 = L4[c];
          float v0 = cand_val(s, a4.x, am, als, l4.x, mB, lsB);
          float v1 = cand_val(s, a4.y, am, als, l4.y, mB, lsB);
          float v2 = cand_val(s, a4.z, am, als, l4.z, mB, lsB);
          float v3 = cand_val(s, a4.w, am, als, l4.w, mB, lsB);
          cm = fmaxf(fmaxf(v0, v1), fmaxf(v2, v3));
        }
        chm[q] = cm; tm = fmaxf(tm, cm);
      }
      float vs = bitonic64_desc_val(tm, lane);
      if (lane == 15) s_ftau[w] = vs;
      __syncthreads();
      float tg = fmaxf(fmaxf(s_ftau[0], s_ftau[1]), fmaxf(s_ftau[2], s_ftau[3]));
#pragma unroll
      for (int q = 0; q < 5; ++q) {
        if (chm[q] >= tg) {
          int c = tid + (q << 8);
          float4 a4 = A4[c]; float4 l4 = L4[c];
          float ar4[4] = {a4.x, a4.y, a4.z, a4.w};
          float lr4[4] = {l4.x, l4.y, l4.z, l4.w};
#pragma unroll
          for (int i = 0; i < 4; ++i) {
            float v = cand_val(s, ar4[i], am, als, lr4[i], mB, lsB);
            if (v >= tg) {
              int p = atomicAdd(&s_fcnt, 1);
              if (p < FCAP) { s_cv[p] = v; s_ct[p] = c * 4 + i; }
            }
          }
        }
      }
      __syncthreads();
      int n = s_fcnt; if (n > FCAP) n = FCAP;
      {
        float v0 = (tid < n) ? s_cv[tid] : -INFINITY;
        int   t0 = (tid < n) ? s_ct[tid] : 0;
        float v1 = (tid + 256 < n) ? s_cv[tid + 256] : -INFINITY;
        int   t1 = (tid + 256 < n) ? s_ct[tid + 256] : 0;
        unsigned long long k0 = ((unsigned long long)fkey(v0) << 13) | (unsigned)(8191 - t0);
        unsigned long long k1 = ((unsigned long long)fkey(v1) << 13) | (unsigned)(8191 - t1);
        int r0 = 0, r1 = 0;
        for (int j = 0; j < n; ++j) {
          unsigned long long kj = ((unsigned long long)fkey(s_cv[j]) << 13) | (unsigned)(8191 - s_ct[j]);
          r0 += (kj > k0) ? 1 : 0;
          r1 += (kj > k1) ? 1 : 0;
        }
        __syncthreads();
        if (tid < n && r0 < BEAMW)       { s_selv[r0] = v0; s_seli[r0] = b * VV + t0; }
        if (tid + 256 < n && r1 < BEAMW) { s_selv[r1] = v1; s_seli[r1] = b * VV + t1; }
      }
      __syncthreads();

      if (tid == 0) {
        unsigned long long* R = (unsigned long long*)(C + 592 + b * 32);
        for (int k = 0; k < BEAMW; ++k) {
          unsigned long long pk = ((unsigned long long)(unsigned int)s_seli[k] << 32)
                                | (unsigned long long)__float_as_uint(s_selv[k]);
          __hip_atomic_store(&R[k], pk, __ATOMIC_RELAXED, __HIP_MEMORY_SCOPE_AGENT);
        }
        __hip_atomic_fetch_add(&C[18], 1u, __ATOMIC_RELEASE, __HIP_MEMORY_SCOPE_AGENT);
        int gd = 0;
        while (__hip_atomic_load(&C[18], __ATOMIC_ACQUIRE, __HIP_MEMORY_SCOPE_AGENT) < (unsigned)(BEAMW * redo_epoch)) {
          __builtin_amdgcn_s_sleep(2);
          if (++gd > 4000000) break;
        }
      }
      __syncthreads();
      {
        const unsigned long long* R = (const unsigned long long*)(C + 592 + (tid >> 4) * 32);
        unsigned long long pk = __hip_atomic_load(&R[tid & 15], __ATOMIC_RELAXED, __HIP_MEMORY_SCOPE_AGENT);
        s_cv[tid] = __uint_as_float((unsigned int)pk);
        s_ct[tid] = (int)(unsigned int)(pk >> 32);
      }
      __syncthreads();
      merge256();
    }

    // ---- next state (each WG local) + WG0 history ----
    if (b == 0 && tid < BEAMW) {
      int fl = s_seli[tid];
      int bp = fl / VV; int tok = fl - bp * VV;
      s_toks[t * BEAMW + tid] = (unsigned short)tok;
      s_bps[t * BEAMW + tid]  = (unsigned char)bp;
    }
    {
      float nv = s_selv[b]; int fl = s_seli[b];
      int bp = fl / VV; int tok = fl - bp * VV;
      s = nv; last = tok;
    }
    lst = lstat4[last];
    __syncthreads();
  }

  // ---- output (WG0) ----
  if (b == 0 && tid < BEAMW) {
    out[tid] = s_selv[tid];
    int ptr = tid;
    for (int tt = TT - 1; tt >= 0; --tt) {
      int tok = (int)s_toks[tt * BEAMW + ptr];
      out[BEAMW + tid * TT + tt] = (float)tok;
      ptr = (int)s_bps[tt * BEAMW + ptr];
    }
  }
}

// ---------------- fallback: single-WG full-scan kernel (ws too small) ----
__global__ __launch_bounds__(1024, 4) void beam_slow(
    const float* __restrict__ asr, const float* __restrict__ lm,
    const float* __restrict__ ws, float* __restrict__ out)
{
  __shared__ float s_scores[BEAMW];
  __shared__ int   s_last[BEAMW];
  __shared__ float s_lmm[BEAMW], s_lmls[BEAMW];
  __shared__ float s_tau[BEAMW];
  __shared__ float s_bufval[FCAP];
  __shared__ int   s_bufidx[FCAP];
  __shared__ int   s_cnt;
  __shared__ unsigned short s_toks[TT * BEAMW];
  __shared__ unsigned char  s_bps[TT * BEAMW];

  const int tid = (int)threadIdx.x;
  const int lane = tid & 63;
  const int w = tid >> 6;
  const float4* __restrict__ lstat4 = (const float4*)(ws + OFF_LSTAT4);

  if (tid < BEAMW) {
    s_scores[tid] = (tid == 0) ? 0.0f : -1e30f;
    s_last[tid] = SOS_TOK;
    float4 st = lstat4[SOS_TOK];
    s_lmm[tid] = st.x; s_lmls[tid] = st.y;
  }
  if (tid == 0) s_cnt = 0;
  __syncthreads();

  for (int t = 0; t < TT; ++t) {
    const float s = s_scores[w];
    const float mB = s_lmm[w], lsB = s_lmls[w];
    const int lastb = s_last[w];
    const float am = ws[OFF_AM + t], als = ws[OFF_ALS + t];
    const float4* __restrict__ L4p = (const float4*)(lm + (size_t)lastb * VV);
    const float4* __restrict__ A4p = (const float4*)(asr + (size_t)t * VV);

    float chm[20]; float rowm = -INFINITY;
#pragma unroll
    for (int k = 0; k < 20; ++k) {
      int c = lane + 64 * k;
      bool ok = (c < NC4);
      int cc = ok ? c : 0;
      float4 A4 = A4p[cc]; float4 L4 = L4p[cc];
      float vx = cand_val(s, A4.x, am, als, L4.x, mB, lsB);
      float vy = cand_val(s, A4.y, am, als, L4.y, mB, lsB);
      float vz = cand_val(s, A4.z, am, als, L4.z, mB, lsB);
      float vw = cand_val(s, A4.w, am, als, L4.w, mB, lsB);
      float cm = fmaxf(fmaxf(vx, vy), fmaxf(vz, vw));
      if (!ok) cm = -INFINITY;
      chm[k] = cm; rowm = fmaxf(rowm, cm);
    }
    {
      float v = bitonic64_desc_val(rowm, lane);
      if (lane == 15) s_tau[w] = v;
    }
    if (tid == 0) s_cnt = 0;
    __syncthreads();

    float tg = s_tau[lane & 15];
#pragma unroll
    for (int j = 1; j <= 8; j <<= 1) tg = fmaxf(tg, __shfl_xor(tg, j, 64));

#pragma unroll
    for (int k = 0; k < 20; ++k) {
      if (chm[k] >= tg) {
        int c = lane + 64 * k;
        float4 A4 = A4p[c]; float4 L4 = L4p[c];
        float ar4[4] = {A4.x, A4.y, A4.z, A4.w};
        float lr4[4] = {L4.x, L4.y, L4.z, L4.w};
#pragma unroll
        for (int i = 0; i < 4; ++i) {
          float v = cand_val(s, ar4[i], am, als, lr4[i], mB, lsB);
          if (v >= tg) {
            int p = atomicAdd(&s_cnt, 1);
            if (p < FCAP) { s_bufval[p] = v; s_bufidx[p] = w * VV + c * 4 + i; }
          }
        }
      }
    }
    __syncthreads();

    if (w == 0) {
      int n = s_cnt; if (n > FCAP) n = FCAP;
      if (n <= 64) {
        float bv = (lane < n) ? s_bufval[lane] : -INFINITY;
        int   bi = (lane < n) ? s_bufidx[lane] : 0x7FFFFFFF;
        bitonic64_desc_pair(bv, bi, lane);
        if (lane < BEAMW) {
          int flat = bi;
          int bb = flat / VV; int tok = flat - bb * VV;
          float4 st = lstat4[tok];
          s_scores[lane] = bv; s_last[lane] = tok;
          s_lmm[lane] = st.x; s_lmls[lane] = st.y;
          s_toks[t * BEAMW + lane] = (unsigned short)tok;
          s_bps[t * BEAMW + lane] = (unsigned char)bb;
        }
      } else {
        float pv = -INFINITY; int pi = 0x7FFFFFFF;
        for (int it = 0; it < BEAMW; ++it) {
          float cvv = -INFINITY; int cii = 0x7FFFFFFF;
          for (int k2 = 0; k2 < FCAP / 64; ++k2) {
            int p = lane + 64 * k2;
            if (p < n) {
              float vv2 = s_bufval[p]; int ii2 = s_bufidx[p];
              bool lessPrev = (it == 0) || (vv2 < pv) || (vv2 == pv && ii2 > pi);
              bool better = (vv2 > cvv) || (vv2 == cvv && ii2 < cii);
              if (lessPrev && better) { cvv = vv2; cii = ii2; }
            }
          }
          for (int j = 1; j < 64; j <<= 1) {
            float ov = __shfl_xor(cvv, j, 64); int oi = __shfl_xor(cii, j, 64);
            bool ob = (ov > cvv) || (ov == cvv && oi < cii);
            if (ob) { cvv = ov; cii = oi; }
          }
          if (lane == 0) {
            int bb = cii / VV; int tok = cii - bb * VV;
            float4 st = lstat4[tok];
            s_scores[it] = cvv; s_last[it] = tok;
            s_lmm[it] = st.x; s_lmls[it] = st.y;
            s_toks[t * BEAMW + it] = (unsigned short)tok;
            s_bps[t * BEAMW + it] = (unsigned char)bb;
          }
          pv = cvv; pi = cii;
        }
      }
    }
    __syncthreads();
  }

  if (tid < BEAMW) {
    out[tid] = s_scores[tid];
    int ptr = tid;
    for (int t = TT - 1; t >= 0; --t) {
      int tok = (int)s_toks[t * BEAMW + ptr];
      out[BEAMW + tid * TT + t] = (float)tok;
      ptr = (int)s_bps[t * BEAMW + ptr];
    }
  }
}

extern "C" void kernel_launch(void* const* d_in, const int* in_sizes, int n_in,
                              void* d_out, int out_size, void* d_ws, size_t ws_size,
                              hipStream_t stream) {
  const float* asr = (const float*)d_in[0];
  const float* lm  = (const float*)d_in[1];
  float* out = (float*)d_out;
  float* ws  = (float*)d_ws;

  int build = (ws_size >= ws_need_floats() * sizeof(float)) ? 1 : 0;
  hipLaunchKernelGGL(prep_kernel, dim3(VV + TT), dim3(256), 0, stream, asr, lm, ws, build);
  if (build)
    hipLaunchKernelGGL(beam_mw, dim3(BEAMW), dim3(256), 0, stream, asr, lm, ws, out);
  else
    hipLaunchKernelGGL(beam_slow, dim3(1), dim3(1024), 0, stream, asr, lm, ws, out);
}